// Round 1
// baseline (96.519 us; speedup 1.0000x reference)
//
#include <hip/hip_runtime.h>

// Problem constants (fixed by setup_inputs)
#define T_   16
#define TOK_ 16384
#define P_   8192
#define N_   32768
#define D_   128
#define L_   8
#define C_   16

constexpr int K1_BLOCKS       = 1024;
constexpr int WAVES_PER_BLOCK = 4;                                   // 256 threads
constexpr int WAVES_PER_T     = K1_BLOCKS * WAVES_PER_BLOCK / T_;    // 256
constexpr int ROWS_PER_WAVE   = P_ / WAVES_PER_T;                    // 32
constexpr int BLOCKS_PER_T    = K1_BLOCKS / T_;                      // 64

// Kernel 1: gather x rows at node_pos, LayerNorm over D=128 (g_enc,b_enc),
// pool 8->1 along D, accumulate per (group l = node_id>>12, c) into
// deterministic per-block partial sums.
__global__ __launch_bounds__(256) void k1_gather_ln_pool(
    const float* __restrict__ x,
    const float* __restrict__ g_enc, const float* __restrict__ b_enc,
    const int* __restrict__ node_pos, const int* __restrict__ node_ids,
    float* __restrict__ partial)
{
    __shared__ float lds[WAVES_PER_BLOCK * 128];
    const int tid  = threadIdx.x;
    const int lane = tid & 63;
    const int wid  = tid >> 6;
    const int W    = blockIdx.x * WAVES_PER_BLOCK + wid;   // global wave id
    const int t    = W >> 8;                               // W / WAVES_PER_T
    const int wv   = W & (WAVES_PER_T - 1);
    const int pbase = wv * ROWS_PER_WAVE;
    const int tP   = t * P_;
    const size_t xbase = (size_t)t * TOK_ * D_;

    // per-lane LN params for its two channels d = 2*lane, 2*lane+1
    const float ge0 = g_enc[2 * lane], ge1 = g_enc[2 * lane + 1];
    const float be0 = b_enc[2 * lane], be1 = b_enc[2 * lane + 1];

    float acc[L_];
#pragma unroll
    for (int ll = 0; ll < L_; ++ll) acc[ll] = 0.f;

    // software pipeline: prefetch row r+1 while computing row r
    int pos = node_pos[tP + pbase];
    int nid = node_ids[tP + pbase];
    float2 v = *reinterpret_cast<const float2*>(x + xbase + (size_t)pos * D_ + lane * 2);

    for (int r = 0; r < ROWS_PER_WAVE; ++r) {
        float2 vn = v;
        int nidn = nid;
        if (r + 1 < ROWS_PER_WAVE) {
            const int posn = node_pos[tP + pbase + r + 1];
            nidn = node_ids[tP + pbase + r + 1];
            vn = *reinterpret_cast<const float2*>(x + xbase + (size_t)posn * D_ + lane * 2);
        }
        // LayerNorm over 128 elements (2 per lane, wave64 reduce)
        float s  = v.x + v.y;
        float ss = v.x * v.x + v.y * v.y;
#pragma unroll
        for (int m = 1; m < 64; m <<= 1) {
            s  += __shfl_xor(s, m);
            ss += __shfl_xor(ss, m);
        }
        const float mean = s * (1.f / 128.f);
        const float var  = ss * (1.f / 128.f) - mean * mean;
        const float rstd = rsqrtf(var + 1e-5f);
        const float xn0 = (v.x - mean) * rstd * ge0 + be0;
        const float xn1 = (v.y - mean) * rstd * ge1 + be1;
        const float srow = xn0 + xn1;   // both channels belong to c = lane>>2
        const int l = nid >> 12;        // group of this row's node id
#pragma unroll
        for (int ll = 0; ll < L_; ++ll) acc[ll] += (ll == l) ? srow : 0.f;
        v = vn; nid = nidn;
    }

    // combine lanes 4c..4c+3 (they share pooled channel c = lane>>2)
#pragma unroll
    for (int ll = 0; ll < L_; ++ll) {
        acc[ll] += __shfl_xor(acc[ll], 1);
        acc[ll] += __shfl_xor(acc[ll], 2);
    }
    const int c = lane >> 2;
    if ((lane & 3) == 0) {
#pragma unroll
        for (int ll = 0; ll < L_; ++ll) lds[wid * 128 + ll * 16 + c] = acc[ll];
    }
    __syncthreads();
    if (tid < 128) {
        const float sum = lds[tid] + lds[128 + tid] + lds[256 + tid] + lds[384 + tid];
        partial[(size_t)blockIdx.x * 128 + tid] = sum;   // deterministic overwrite
    }
}

// Kernel 2: reduce partials per t, scale, LN over 128 (g_fin,b_fin),
// LN over 16-element groups (g_dec,b_dec) -> decoded[t*128 + l*16 + c]
__global__ __launch_bounds__(64) void k2_finalize(
    const float* __restrict__ partial,
    const float* __restrict__ g_fin, const float* __restrict__ b_fin,
    const float* __restrict__ g_dec, const float* __restrict__ b_dec,
    float* __restrict__ decoded)
{
    const int t = blockIdx.x;
    const int lane = threadIdx.x;
    const float* pb = partial + (size_t)t * BLOCKS_PER_T * 128;
    float a0 = 0.f, a1 = 0.f;
    for (int k = 0; k < BLOCKS_PER_T; ++k) {
        a0 += pb[k * 128 + lane];
        a1 += pb[k * 128 + 64 + lane];
    }
    // comp = raw_sum / (4096 groups * 8 pooled)
    a0 *= (1.f / 32768.f);
    a1 *= (1.f / 32768.f);

    // LN over all 128 (lane holds i=lane and i=lane+64)
    float s = a0 + a1, ss = a0 * a0 + a1 * a1;
#pragma unroll
    for (int m = 1; m < 64; m <<= 1) {
        s  += __shfl_xor(s, m);
        ss += __shfl_xor(ss, m);
    }
    const float mean = s * (1.f / 128.f);
    const float rstd = rsqrtf(ss * (1.f / 128.f) - mean * mean + 1e-5f);
    const float c0 = (a0 - mean) * rstd * g_fin[lane]      + b_fin[lane];
    const float c1 = (a1 - mean) * rstd * g_fin[lane + 64] + b_fin[lane + 64];

    // LN over each group of 16 (lanes 16g..16g+15 hold group g for c0; g+4 for c1)
    float s0 = c0, q0 = c0 * c0, s1 = c1, q1 = c1 * c1;
#pragma unroll
    for (int m = 1; m < 16; m <<= 1) {
        s0 += __shfl_xor(s0, m); q0 += __shfl_xor(q0, m);
        s1 += __shfl_xor(s1, m); q1 += __shfl_xor(q1, m);
    }
    const float m0 = s0 * (1.f / 16.f), m1 = s1 * (1.f / 16.f);
    const float r0 = rsqrtf(q0 * (1.f / 16.f) - m0 * m0 + 1e-5f);
    const float r1 = rsqrtf(q1 * (1.f / 16.f) - m1 * m1 + 1e-5f);
    const int c = lane & 15;
    const float gd = g_dec[c], bd = b_dec[c];
    decoded[t * 128 + lane]      = (c0 - m0) * r0 * gd + bd;
    decoded[t * 128 + 64 + lane] = (c1 - m1) * r1 * gd + bd;
}

// Kernel 3: out[t,n,d] = decoded[t, n>>12, d>>3]; coalesced float4 stores.
__global__ __launch_bounds__(256) void k3_broadcast(
    const float* __restrict__ decoded, float4* __restrict__ out)
{
    const int total = T_ * N_ * (D_ / 4);   // 16,777,216 float4 stores
    const int stride = gridDim.x * blockDim.x;
    for (int q = blockIdx.x * blockDim.x + threadIdx.x; q < total; q += stride) {
        const int d4 = q & 31;              // float4 index within row (D/4 = 32)
        const int n  = (q >> 5) & (N_ - 1);
        const int t  = q >> 20;             // 32768*32 = 2^20 float4 per t
        const float val = decoded[(t << 7) + ((n >> 12) << 4) + (d4 >> 1)];
        out[q] = make_float4(val, val, val, val);
    }
}

extern "C" void kernel_launch(void* const* d_in, const int* in_sizes, int n_in,
                              void* d_out, int out_size, void* d_ws, size_t ws_size,
                              hipStream_t stream)
{
    const float* x      = (const float*)d_in[0];
    const float* g_enc  = (const float*)d_in[1];
    const float* b_enc  = (const float*)d_in[2];
    const float* g_fin  = (const float*)d_in[3];
    const float* b_fin  = (const float*)d_in[4];
    const float* g_dec  = (const float*)d_in[5];
    const float* b_dec  = (const float*)d_in[6];
    const int*   node_pos = (const int*)d_in[7];
    const int*   node_ids = (const int*)d_in[8];
    // d_in[9] = num_nodes (compile-time constant N_ here)

    float* partial = (float*)d_ws;                         // 1024*128 f32 = 512 KB
    float* decoded = partial + (size_t)K1_BLOCKS * 128;    // 2048 f32
    float* out = (float*)d_out;

    hipLaunchKernelGGL(k1_gather_ln_pool, dim3(K1_BLOCKS), dim3(256), 0, stream,
                       x, g_enc, b_enc, node_pos, node_ids, partial);
    hipLaunchKernelGGL(k2_finalize, dim3(T_), dim3(64), 0, stream,
                       partial, g_fin, b_fin, g_dec, b_dec, decoded);
    hipLaunchKernelGGL(k3_broadcast, dim3(2048), dim3(256), 0, stream,
                       decoded, (float4*)out);
}

// Round 3
// 82.741 us; speedup vs baseline: 1.1665x; 1.1665x over previous
//
#include <hip/hip_runtime.h>

// Problem constants (fixed by setup_inputs)
#define T_   16
#define TOK_ 16384
#define P_   8192
#define N_   32768
#define D_   128
#define L_   8
#define C_   16

typedef float f32x2 __attribute__((ext_vector_type(2)));
typedef float f32x4 __attribute__((ext_vector_type(4)));

constexpr int K1_BLOCKS     = 1024;
constexpr int BLOCKS_PER_T  = 64;    // K1 producer blocks per timestamp
constexpr int ROWS_PER_WAVE = 32;    // 8192 rows / (64 blocks * 4 waves)

// ---------------------------------------------------------------------------
// Kernel 1: gather x rows at node_pos, LayerNorm over D=128 (g_enc,b_enc),
// pool 8->1 along D (sum within lane pairs), accumulate per group
// l = node_id>>12 into deterministic per-block partials.
// Rows are processed 4 at a time with a 4-deep gather pipeline; all 32 row
// indices are preloaded into lanes (one coalesced load) so the index fetch
// is off the critical path.
// ---------------------------------------------------------------------------
__global__ __launch_bounds__(256) void k1_gather_ln_pool(
    const float* __restrict__ x,
    const float* __restrict__ g_enc, const float* __restrict__ b_enc,
    const int* __restrict__ node_pos, const int* __restrict__ node_ids,
    float* __restrict__ partial)
{
    __shared__ float lds[4 * 128];
    const int tid   = threadIdx.x;
    const int lane  = tid & 63;
    const int wid   = tid >> 6;
    const int b     = blockIdx.x;
    const int t     = b >> 6;          // 64 blocks per t
    const int chunk = b & 63;
    const int pbase = chunk * 128 + wid * ROWS_PER_WAVE;
    const int tP    = t * P_;
    const float* xt = x + (size_t)t * TOK_ * D_ + 2 * lane;

    // per-lane LN params for channels d = 2*lane, 2*lane+1
    const float ge0 = g_enc[2 * lane], ge1 = g_enc[2 * lane + 1];
    const float be0 = b_enc[2 * lane], be1 = b_enc[2 * lane + 1];

    // lanes 0..31 hold this wave's 32 row indices (lanes 32..63 duplicate)
    const int posv = node_pos[tP + pbase + (lane & 31)];
    const int nidv = node_ids[tP + pbase + (lane & 31)];

    float acc[L_];
#pragma unroll
    for (int ll = 0; ll < L_; ++ll) acc[ll] = 0.f;

    // 4-deep gather pipeline
    f32x2 b0, b1, b2, b3;
    {
        int p0 = __shfl(posv, 0), p1 = __shfl(posv, 1);
        int p2 = __shfl(posv, 2), p3 = __shfl(posv, 3);
        b0 = __builtin_nontemporal_load((const f32x2*)(xt + (size_t)p0 * D_));
        b1 = __builtin_nontemporal_load((const f32x2*)(xt + (size_t)p1 * D_));
        b2 = __builtin_nontemporal_load((const f32x2*)(xt + (size_t)p2 * D_));
        b3 = __builtin_nontemporal_load((const f32x2*)(xt + (size_t)p3 * D_));
    }

#pragma unroll
    for (int g = 0; g < ROWS_PER_WAVE / 4; ++g) {
        f32x2 c0 = b0, c1 = b1, c2 = b2, c3 = b3;
        if (g < ROWS_PER_WAVE / 4 - 1) {
            const int rb = (g + 1) * 4;
            int p0 = __shfl(posv, rb + 0), p1 = __shfl(posv, rb + 1);
            int p2 = __shfl(posv, rb + 2), p3 = __shfl(posv, rb + 3);
            b0 = __builtin_nontemporal_load((const f32x2*)(xt + (size_t)p0 * D_));
            b1 = __builtin_nontemporal_load((const f32x2*)(xt + (size_t)p1 * D_));
            b2 = __builtin_nontemporal_load((const f32x2*)(xt + (size_t)p2 * D_));
            b3 = __builtin_nontemporal_load((const f32x2*)(xt + (size_t)p3 * D_));
        }
        // 4 independent LN reduce chains (ILP across the shuffle trees)
        float s0 = c0.x + c0.y, q0 = c0.x * c0.x + c0.y * c0.y;
        float s1 = c1.x + c1.y, q1 = c1.x * c1.x + c1.y * c1.y;
        float s2 = c2.x + c2.y, q2 = c2.x * c2.x + c2.y * c2.y;
        float s3 = c3.x + c3.y, q3 = c3.x * c3.x + c3.y * c3.y;
#pragma unroll
        for (int m = 1; m < 64; m <<= 1) {
            s0 += __shfl_xor(s0, m); q0 += __shfl_xor(q0, m);
            s1 += __shfl_xor(s1, m); q1 += __shfl_xor(q1, m);
            s2 += __shfl_xor(s2, m); q2 += __shfl_xor(q2, m);
            s3 += __shfl_xor(s3, m); q3 += __shfl_xor(q3, m);
        }
#pragma unroll
        for (int k = 0; k < 4; ++k) {
            const f32x2 v = (k == 0) ? c0 : (k == 1) ? c1 : (k == 2) ? c2 : c3;
            const float s = (k == 0) ? s0 : (k == 1) ? s1 : (k == 2) ? s2 : s3;
            const float q = (k == 0) ? q0 : (k == 1) ? q1 : (k == 2) ? q2 : q3;
            const float mean = s * (1.f / 128.f);
            const float rstd = rsqrtf(q * (1.f / 128.f) - mean * mean + 1e-5f);
            const float srow = (v.x - mean) * rstd * ge0 + be0
                             + (v.y - mean) * rstd * ge1 + be1;
            const int l = __shfl(nidv, g * 4 + k) >> 12;
#pragma unroll
            for (int ll = 0; ll < L_; ++ll) acc[ll] += (ll == l) ? srow : 0.f;
        }
    }

    // combine lanes 4c..4c+3 (they share pooled channel c = lane>>2)
#pragma unroll
    for (int ll = 0; ll < L_; ++ll) {
        acc[ll] += __shfl_xor(acc[ll], 1);
        acc[ll] += __shfl_xor(acc[ll], 2);
    }
    const int c = lane >> 2;
    if ((lane & 3) == 0) {
#pragma unroll
        for (int ll = 0; ll < L_; ++ll) lds[wid * 128 + ll * 16 + c] = acc[ll];
    }
    __syncthreads();
    if (tid < 128) {
        const float sum = lds[tid] + lds[128 + tid] + lds[256 + tid] + lds[384 + tid];
        partial[(size_t)b * 128 + tid] = sum;   // deterministic overwrite
    }
}

// ---------------------------------------------------------------------------
// Kernel 2: reduce 64 partials per t, scale, LN over 128 (g_fin,b_fin),
// LN over 16-element groups (g_dec,b_dec) -> decoded[t*128 + l*16 + c]
// ---------------------------------------------------------------------------
__global__ __launch_bounds__(64) void k2_finalize(
    const float* __restrict__ partial,
    const float* __restrict__ g_fin, const float* __restrict__ b_fin,
    const float* __restrict__ g_dec, const float* __restrict__ b_dec,
    float* __restrict__ decoded)
{
    const int t = blockIdx.x;
    const int lane = threadIdx.x;
    const float* pb = partial + (size_t)t * BLOCKS_PER_T * 128;
    float a0 = 0.f, a1 = 0.f;
#pragma unroll 8
    for (int k = 0; k < BLOCKS_PER_T; ++k) {
        a0 += pb[k * 128 + lane];
        a1 += pb[k * 128 + 64 + lane];
    }
    a0 *= (1.f / 32768.f);   // /4096 scatter slots /8 pooled
    a1 *= (1.f / 32768.f);

    float s = a0 + a1, ss = a0 * a0 + a1 * a1;
#pragma unroll
    for (int m = 1; m < 64; m <<= 1) {
        s  += __shfl_xor(s, m);
        ss += __shfl_xor(ss, m);
    }
    const float mean = s * (1.f / 128.f);
    const float rstd = rsqrtf(ss * (1.f / 128.f) - mean * mean + 1e-5f);
    const float c0 = (a0 - mean) * rstd * g_fin[lane]      + b_fin[lane];
    const float c1 = (a1 - mean) * rstd * g_fin[lane + 64] + b_fin[lane + 64];

    float s0 = c0, q0 = c0 * c0, s1 = c1, q1 = c1 * c1;
#pragma unroll
    for (int m = 1; m < 16; m <<= 1) {
        s0 += __shfl_xor(s0, m); q0 += __shfl_xor(q0, m);
        s1 += __shfl_xor(s1, m); q1 += __shfl_xor(q1, m);
    }
    const float m0 = s0 * (1.f / 16.f), m1 = s1 * (1.f / 16.f);
    const float r0 = rsqrtf(q0 * (1.f / 16.f) - m0 * m0 + 1e-5f);
    const float r1 = rsqrtf(q1 * (1.f / 16.f) - m1 * m1 + 1e-5f);
    const int c = lane & 15;
    const float gd = g_dec[c], bd = b_dec[c];
    decoded[t * 128 + lane]      = (c0 - m0) * r0 * gd + bd;
    decoded[t * 128 + 64 + lane] = (c1 - m1) * r1 * gd + bd;
}

// ---------------------------------------------------------------------------
// Kernel 3: out[t,n,d] = decoded[t, n>>12, d>>3].
// 2048 blocks; block b covers one contiguous 128 KB slice of one (t, l):
//   t = b>>7, chunk = b&127 -> rows chunk*256..+255, all with l = chunk>>4.
// Because 256 % 32 == 0, a thread's float4-column d4 = tid&31 is constant,
// so its broadcast value is constant: pure nontemporal store stream.
// ---------------------------------------------------------------------------
__global__ __launch_bounds__(256) void k3_broadcast(
    const float* __restrict__ decoded, f32x4* __restrict__ out)
{
    const int tid   = threadIdx.x;
    const int b     = blockIdx.x;
    const int t     = b >> 7;
    const int chunk = b & 127;
    const int l     = chunk >> 4;                 // 16 blocks per l-group
    const float val = decoded[(t << 7) + (l << 4) + ((tid & 31) >> 1)];
    const f32x4 v4 = {val, val, val, val};
    f32x4* p = out + (((size_t)t << 20) + ((size_t)chunk << 13) + tid);
#pragma unroll
    for (int it = 0; it < 32; ++it)
        __builtin_nontemporal_store(v4, p + (it << 8));
}

extern "C" void kernel_launch(void* const* d_in, const int* in_sizes, int n_in,
                              void* d_out, int out_size, void* d_ws, size_t ws_size,
                              hipStream_t stream)
{
    const float* x      = (const float*)d_in[0];
    const float* g_enc  = (const float*)d_in[1];
    const float* b_enc  = (const float*)d_in[2];
    const float* g_fin  = (const float*)d_in[3];
    const float* b_fin  = (const float*)d_in[4];
    const float* g_dec  = (const float*)d_in[5];
    const float* b_dec  = (const float*)d_in[6];
    const int*   node_pos = (const int*)d_in[7];
    const int*   node_ids = (const int*)d_in[8];

    float* partial = (float*)d_ws;                         // 1024*128 f32 = 512 KB
    float* decoded = partial + (size_t)K1_BLOCKS * 128;    // 2048 f32
    float* out = (float*)d_out;

    hipLaunchKernelGGL(k1_gather_ln_pool, dim3(K1_BLOCKS), dim3(256), 0, stream,
                       x, g_enc, b_enc, node_pos, node_ids, partial);
    hipLaunchKernelGGL(k2_finalize, dim3(T_), dim3(64), 0, stream,
                       partial, g_fin, b_fin, g_dec, b_dec, decoded);
    hipLaunchKernelGGL(k3_broadcast, dim3(2048), dim3(256), 0, stream,
                       decoded, (f32x4*)out);
}

// Round 4
// 72.688 us; speedup vs baseline: 1.3278x; 1.1383x over previous
//
#include <hip/hip_runtime.h>

// Problem constants (fixed by setup_inputs)
#define T_   16
#define TOK_ 16384
#define P_   8192
#define N_   32768
#define D_   128
#define L_   8
#define C_   16

typedef float f32x2 __attribute__((ext_vector_type(2)));
typedef float f32x4 __attribute__((ext_vector_type(4)));

constexpr int K1_BLOCKS     = 2048;
constexpr int BLOCKS_PER_T  = 128;   // K1 producer blocks per timestamp
constexpr int ROWS_PER_WAVE = 16;    // 8192 rows / (128 blocks * 4 waves)

// ---------------------------------------------------------------------------
// Kernel 1: gather x rows at node_pos, LayerNorm over D=128 (g_enc,b_enc),
// pool 8->1, accumulate per group l = node_id>>12 into per-block partials.
//
// Layout: 16 lanes per row (quarter-wave q = lane>>4 owns row i*4+q of the
// wave's 16 rows; sublane j = lane&15 owns pooled channel c=j, i.e. elements
// d = 8j..8j+7). LN reduce = 4 shfl_xor levels shared by 4 rows at once.
// Pool fuses algebraically: sum_c = (dot(v,g) - mean*sum(g))*rstd + sum(b).
// All 8 gather loads (4 rows-in-flight batches x 2 f32x4) issue up-front ->
// one memory round-trip per wave. Loads are CACHED (x is L3-resident; K3's
// nt stores bypass L3 and keep it so).
// ---------------------------------------------------------------------------
__global__ __launch_bounds__(256) void k1_gather_ln_pool(
    const float* __restrict__ x,
    const float* __restrict__ g_enc, const float* __restrict__ b_enc,
    const int* __restrict__ node_pos, const int* __restrict__ node_ids,
    float* __restrict__ partial)
{
    __shared__ float lds[4 * 128];
    const int tid   = threadIdx.x;
    const int lane  = tid & 63;
    const int wid   = tid >> 6;
    const int j     = lane & 15;   // channel
    const int q     = lane >> 4;   // quarter (row within batch)
    const int b     = blockIdx.x;
    const int t     = b >> 7;      // 128 blocks per t
    const int chunk = b & 127;
    const int pbase = chunk * 64 + wid * ROWS_PER_WAVE;
    const int tP    = t * P_;
    const float* xt = x + (size_t)t * TOK_ * D_;

    // per-lane LN params for elements d = 8j..8j+7
    const f32x4 g0 = *(const f32x4*)(g_enc + 8 * j);
    const f32x4 g1 = *(const f32x4*)(g_enc + 8 * j + 4);
    const f32x4 bb0 = *(const f32x4*)(b_enc + 8 * j);
    const f32x4 bb1 = *(const f32x4*)(b_enc + 8 * j + 4);
    const float G = g0.x + g0.y + g0.z + g0.w + g1.x + g1.y + g1.z + g1.w;
    const float B = bb0.x + bb0.y + bb0.z + bb0.w + bb1.x + bb1.y + bb1.z + bb1.w;

    // lanes 0..15 hold the wave's 16 row indices (other lanes duplicate)
    const int posv = node_pos[tP + pbase + j];
    const int nidv = node_ids[tP + pbase + j];

    // issue ALL gather loads up-front: row r = i*4+q, lane reads d=8j..8j+7
    f32x4 va[4], vb[4];
#pragma unroll
    for (int i = 0; i < 4; ++i) {
        const int p = __shfl(posv, i * 4 + q);
        const float* row = xt + (size_t)p * D_ + 8 * j;
        va[i] = *(const f32x4*)(row);
        vb[i] = *(const f32x4*)(row + 4);
    }

    float acc[L_];
#pragma unroll
    for (int ll = 0; ll < L_; ++ll) acc[ll] = 0.f;

#pragma unroll
    for (int i = 0; i < 4; ++i) {
        const f32x4 a = va[i], c = vb[i];
        float s  = a.x + a.y + a.z + a.w + c.x + c.y + c.z + c.w;
        float ss = a.x*a.x + a.y*a.y + a.z*a.z + a.w*a.w
                 + c.x*c.x + c.y*c.y + c.z*c.z + c.w*c.w;
        float dot = a.x*g0.x + a.y*g0.y + a.z*g0.z + a.w*g0.w
                  + c.x*g1.x + c.y*g1.y + c.z*g1.z + c.w*g1.w;
        // LN stats over the row's 128 elements: reduce across 16 lanes
#pragma unroll
        for (int m = 1; m < 16; m <<= 1) {
            s  += __shfl_xor(s, m);
            ss += __shfl_xor(ss, m);
        }
        const float mean = s * (1.f / 128.f);
        const float rstd = rsqrtf(ss * (1.f / 128.f) - mean * mean + 1e-5f);
        const float srow = (dot - mean * G) * rstd + B;   // channel-c pooled sum
        const int l = __shfl(nidv, i * 4 + q) >> 12;
#pragma unroll
        for (int ll = 0; ll < L_; ++ll) acc[ll] += (ll == l) ? srow : 0.f;
    }

    // combine quarters (lanes j, j+16, j+32, j+48 share channel j)
#pragma unroll
    for (int ll = 0; ll < L_; ++ll) {
        acc[ll] += __shfl_xor(acc[ll], 16);
        acc[ll] += __shfl_xor(acc[ll], 32);
    }
    if (lane < 16) {
#pragma unroll
        for (int ll = 0; ll < L_; ++ll) lds[wid * 128 + ll * 16 + j] = acc[ll];
    }
    __syncthreads();
    if (tid < 128) {
        const float sum = lds[tid] + lds[128 + tid] + lds[256 + tid] + lds[384 + tid];
        partial[(size_t)b * 128 + tid] = sum;   // deterministic overwrite
    }
}

// ---------------------------------------------------------------------------
// Kernel 2: reduce 128 partials per t, scale, LN over 128 (g_fin,b_fin),
// LN over 16-element groups (g_dec,b_dec) -> decoded[t*128 + l*16 + c]
// ---------------------------------------------------------------------------
__global__ __launch_bounds__(64) void k2_finalize(
    const float* __restrict__ partial,
    const float* __restrict__ g_fin, const float* __restrict__ b_fin,
    const float* __restrict__ g_dec, const float* __restrict__ b_dec,
    float* __restrict__ decoded)
{
    const int t = blockIdx.x;
    const int lane = threadIdx.x;
    const float* pb = partial + (size_t)t * BLOCKS_PER_T * 128;
    float a0 = 0.f, a1 = 0.f;
#pragma unroll 8
    for (int k = 0; k < BLOCKS_PER_T; ++k) {
        a0 += pb[k * 128 + lane];
        a1 += pb[k * 128 + 64 + lane];
    }
    a0 *= (1.f / 32768.f);   // /4096 scatter slots /8 pooled
    a1 *= (1.f / 32768.f);

    float s = a0 + a1, ss = a0 * a0 + a1 * a1;
#pragma unroll
    for (int m = 1; m < 64; m <<= 1) {
        s  += __shfl_xor(s, m);
        ss += __shfl_xor(ss, m);
    }
    const float mean = s * (1.f / 128.f);
    const float rstd = rsqrtf(ss * (1.f / 128.f) - mean * mean + 1e-5f);
    const float c0 = (a0 - mean) * rstd * g_fin[lane]      + b_fin[lane];
    const float c1 = (a1 - mean) * rstd * g_fin[lane + 64] + b_fin[lane + 64];

    float s0 = c0, q0 = c0 * c0, s1 = c1, q1 = c1 * c1;
#pragma unroll
    for (int m = 1; m < 16; m <<= 1) {
        s0 += __shfl_xor(s0, m); q0 += __shfl_xor(q0, m);
        s1 += __shfl_xor(s1, m); q1 += __shfl_xor(q1, m);
    }
    const float m0 = s0 * (1.f / 16.f), m1 = s1 * (1.f / 16.f);
    const float r0 = rsqrtf(q0 * (1.f / 16.f) - m0 * m0 + 1e-5f);
    const float r1 = rsqrtf(q1 * (1.f / 16.f) - m1 * m1 + 1e-5f);
    const int c = lane & 15;
    const float gd = g_dec[c], bd = b_dec[c];
    decoded[t * 128 + lane]      = (c0 - m0) * r0 * gd + bd;
    decoded[t * 128 + 64 + lane] = (c1 - m1) * r1 * gd + bd;
}

// ---------------------------------------------------------------------------
// Kernel 3: out[t,n,d] = decoded[t, n>>12, d>>3].
// 2048 blocks; block b covers one contiguous 128 KB slice of one (t, l).
// A thread's float4-column d4 = tid&31 is constant -> constant broadcast
// value -> pure nontemporal store stream (bypasses L2/L3, preserves x in L3).
// ---------------------------------------------------------------------------
__global__ __launch_bounds__(256) void k3_broadcast(
    const float* __restrict__ decoded, f32x4* __restrict__ out)
{
    const int tid   = threadIdx.x;
    const int b     = blockIdx.x;
    const int t     = b >> 7;
    const int chunk = b & 127;
    const int l     = chunk >> 4;                 // 16 blocks per l-group
    const float val = decoded[(t << 7) + (l << 4) + ((tid & 31) >> 1)];
    const f32x4 v4 = {val, val, val, val};
    f32x4* p = out + (((size_t)t << 20) + ((size_t)chunk << 13) + tid);
#pragma unroll
    for (int it = 0; it < 32; ++it)
        __builtin_nontemporal_store(v4, p + (it << 8));
}

extern "C" void kernel_launch(void* const* d_in, const int* in_sizes, int n_in,
                              void* d_out, int out_size, void* d_ws, size_t ws_size,
                              hipStream_t stream)
{
    const float* x      = (const float*)d_in[0];
    const float* g_enc  = (const float*)d_in[1];
    const float* b_enc  = (const float*)d_in[2];
    const float* g_fin  = (const float*)d_in[3];
    const float* b_fin  = (const float*)d_in[4];
    const float* g_dec  = (const float*)d_in[5];
    const float* b_dec  = (const float*)d_in[6];
    const int*   node_pos = (const int*)d_in[7];
    const int*   node_ids = (const int*)d_in[8];

    float* partial = (float*)d_ws;                         // 2048*128 f32 = 1 MB
    float* decoded = partial + (size_t)K1_BLOCKS * 128;    // 2048 f32
    float* out = (float*)d_out;

    hipLaunchKernelGGL(k1_gather_ln_pool, dim3(K1_BLOCKS), dim3(256), 0, stream,
                       x, g_enc, b_enc, node_pos, node_ids, partial);
    hipLaunchKernelGGL(k2_finalize, dim3(T_), dim3(64), 0, stream,
                       partial, g_fin, b_fin, g_dec, b_dec, decoded);
    hipLaunchKernelGGL(k3_broadcast, dim3(2048), dim3(256), 0, stream,
                       decoded, (f32x4*)out);
}